// Round 3
// baseline (226.035 us; speedup 1.0000x reference)
//
#include <hip/hip_runtime.h>
#include <hip/hip_bf16.h>
#include <math.h>

#define LSEQ 32768
#define DMODEL 256
#define DHID 256
#define NCH 512                 // interleaved [re,im] hidden channels
#define CHUNK 64
#define NCHUNKS (LSEQ / CHUNK)  // 512

typedef __bf16 bf16_t;
typedef __bf16 bf16x8 __attribute__((ext_vector_type(8)));
typedef __bf16 bf16x2 __attribute__((ext_vector_type(2)));
typedef float f32x4 __attribute__((ext_vector_type(4)));

// ---------------- prep: lambda and lambda^CHUNK (fp64 for phase accuracy) ----
__global__ void prep_params(const float* __restrict__ nu_log,
                            const float* __restrict__ theta_log,
                            float* __restrict__ lam) {
  int h = threadIdx.x;
  double nu = exp((double)nu_log[h]);
  double th = exp((double)theta_log[h]);
  double mag = exp(-nu);
  lam[2 * h]     = (float)(mag * cos(th));
  lam[2 * h + 1] = (float)(mag * sin(th));
  double magC = exp(-(double)CHUNK * nu);
  double phC  = fmod((double)CHUNK * th, 6.283185307179586);
  lam[2 * DHID + 2 * h]     = (float)(magC * cos(phC));
  lam[2 * DHID + 2 * h + 1] = (float)(magC * sin(phC));
}

// W1 rows interleaved: row 2h = B_re[h]*gamma, row 2h+1 = B_im[h]*gamma
__global__ void pack_w1(const float* __restrict__ B_re, const float* __restrict__ B_im,
                        const float* __restrict__ gamma_log, bf16_t* __restrict__ W1) {
  int n = blockIdx.x, k = threadIdx.x;
  int h = n >> 1;
  float g = expf(gamma_log[h]);
  float v = ((n & 1) ? B_im[h * DMODEL + k] : B_re[h * DMODEL + k]) * g;
  W1[n * DMODEL + k] = (bf16_t)v;
}

// W2 cols interleaved to match Hb: W2[m][2h]=C_re[m][h], W2[m][2h+1]=-C_im[m][h]
__global__ void pack_w2(const float* __restrict__ C_re, const float* __restrict__ C_im,
                        bf16_t* __restrict__ W2) {
  int m = blockIdx.x, k = threadIdx.x;  // 512 threads
  int h = k >> 1;
  float v = (k & 1) ? -C_im[m * DHID + h] : C_re[m * DHID + h];
  W2[m * NCH + k] = (bf16_t)v;
}

// ---------------- GEMM1: Bu[L x 512](bf16) = x[L x 256](f32) @ W1[512x256]^T
// Weight-stationary: wave holds 64 cols x 256 k of W1 in 128 VGPRs.
// Block = 4 waves = 256 cols; grid 1024 blocks; block streams 64 rows in
// 4 steps of 16, A prefetched one step ahead. No LDS, no barriers.
__global__ __launch_bounds__(256, 2) void gemm1(
    const float* __restrict__ x, const bf16_t* __restrict__ W1,
    bf16_t* __restrict__ Bu) {
  const int i = blockIdx.x;
  const int colb = (i >> 3) & 1;                 // same-row blocks differ by 8
  const int rowb = (i & 7) | ((i >> 4) << 3);    // -> same XCD under RR dispatch
  const int wave = threadIdx.x >> 6, lane = threadIdx.x & 63;
  const int lrow = lane & 15, lk = lane >> 4;
  const int c0 = colb * 256 + wave * 64;
  const int rbase = rowb * 64;

  // resident B fragments: 4 col-tiles x 8 k-frags
  bf16x8 bw[4][8];
#pragma unroll
  for (int j = 0; j < 4; ++j)
#pragma unroll
    for (int k0 = 0; k0 < 8; ++k0)
      bw[j][k0] = *(const bf16x8*)(W1 + (size_t)(c0 + j * 16 + lrow) * 256 + k0 * 32 + lk * 8);

  float4 cu[8][2];
  {
    const float* ap = x + (size_t)(rbase + lrow) * 256 + lk * 8;
#pragma unroll
    for (int k0 = 0; k0 < 8; ++k0) {
      cu[k0][0] = *(const float4*)(ap + k0 * 32);
      cu[k0][1] = *(const float4*)(ap + k0 * 32 + 4);
    }
  }

#pragma unroll
  for (int step = 0; step < 4; ++step) {
    bf16x8 af[8];
#pragma unroll
    for (int k0 = 0; k0 < 8; ++k0) {
      float4 a = cu[k0][0], b = cu[k0][1];
      bf16x8 t = {(bf16_t)a.x, (bf16_t)a.y, (bf16_t)a.z, (bf16_t)a.w,
                  (bf16_t)b.x, (bf16_t)b.y, (bf16_t)b.z, (bf16_t)b.w};
      af[k0] = t;
    }
    // prefetch next step (clamped; last-iter redundant load is in-bounds)
    {
      int ns = (step < 3) ? step + 1 : 3;
      const float* ap = x + (size_t)(rbase + ns * 16 + lrow) * 256 + lk * 8;
#pragma unroll
      for (int k0 = 0; k0 < 8; ++k0) {
        cu[k0][0] = *(const float4*)(ap + k0 * 32);
        cu[k0][1] = *(const float4*)(ap + k0 * 32 + 4);
      }
    }
    f32x4 acc[4] = {};
#pragma unroll
    for (int k0 = 0; k0 < 8; ++k0)
#pragma unroll
      for (int j = 0; j < 4; ++j)
        acc[j] = __builtin_amdgcn_mfma_f32_16x16x32_bf16(af[k0], bw[j][k0], acc[j], 0, 0, 0);

    const int srow = rbase + step * 16 + lk * 4;
#pragma unroll
    for (int j = 0; j < 4; ++j)
#pragma unroll
      for (int r = 0; r < 4; ++r)
        Bu[(size_t)(srow + r) * NCH + c0 + j * 16 + lrow] = (bf16_t)acc[j][r];
  }
}

// ---------------- GEMM2: out[L x 256](f32) = Hb[L x 512] @ W2[256x512]^T + x*D
// Wave holds 32 cols x 512 k of W2 in 128 VGPRs. Block = 4 waves = 128 cols;
// grid 1024 blocks (2 col-blocks, XCD-swizzled); 4 steps of 16 rows.
__global__ __launch_bounds__(256, 2) void gemm2(
    const bf16_t* __restrict__ Hb, const bf16_t* __restrict__ W2,
    const float* __restrict__ x, const float* __restrict__ Dv,
    float* __restrict__ out) {
  const int i = blockIdx.x;
  const int colb = (i >> 3) & 1;
  const int rowb = (i & 7) | ((i >> 4) << 3);
  const int wave = threadIdx.x >> 6, lane = threadIdx.x & 63;
  const int lrow = lane & 15, lk = lane >> 4;
  const int c0 = colb * 128 + wave * 32;
  const int rbase = rowb * 64;

  bf16x8 bw[2][16];
#pragma unroll
  for (int j = 0; j < 2; ++j)
#pragma unroll
    for (int k0 = 0; k0 < 16; ++k0)
      bw[j][k0] = *(const bf16x8*)(W2 + (size_t)(c0 + j * 16 + lrow) * NCH + k0 * 32 + lk * 8);

  float dv[2];
#pragma unroll
  for (int j = 0; j < 2; ++j) dv[j] = Dv[c0 + j * 16 + lrow];

#pragma unroll
  for (int step = 0; step < 4; ++step) {
    const int r0 = rbase + step * 16;
    const bf16_t* ap = Hb + (size_t)(r0 + lrow) * NCH + lk * 8;
    bf16x8 af[16];
#pragma unroll
    for (int k0 = 0; k0 < 16; ++k0) af[k0] = *(const bf16x8*)(ap + k0 * 32);

    // skip-connection inputs for this step (issued early to overlap MFMA)
    const int srow = r0 + lk * 4;
    float xs[2][4];
#pragma unroll
    for (int j = 0; j < 2; ++j)
#pragma unroll
      for (int r = 0; r < 4; ++r)
        xs[j][r] = x[(size_t)(srow + r) * DMODEL + c0 + j * 16 + lrow];

    f32x4 acc[2][2] = {};
#pragma unroll
    for (int k0 = 0; k0 < 16; ++k0)
#pragma unroll
      for (int j = 0; j < 2; ++j)
        acc[j][k0 & 1] = __builtin_amdgcn_mfma_f32_16x16x32_bf16(af[k0], bw[j][k0], acc[j][k0 & 1], 0, 0, 0);

#pragma unroll
    for (int j = 0; j < 2; ++j)
#pragma unroll
      for (int r = 0; r < 4; ++r) {
        float v = acc[j][0][r] + acc[j][1][r] + xs[j][r] * dv[j];
        out[(size_t)(srow + r) * DMODEL + c0 + j * 16 + lrow] = v;
      }
  }
}

// ---------------- scan pass 1: per-chunk local end state ---------------------
__global__ void scan_pass1(const unsigned int* __restrict__ Bu,
                           const float* __restrict__ lam, float2* __restrict__ E) {
  int c = blockIdx.x, h = threadIdx.x;
  float lre = lam[2 * h], lim = lam[2 * h + 1];
  float sre = 0.f, sim = 0.f;
  const unsigned int* p = Bu + (size_t)c * CHUNK * 256 + h;
#pragma unroll 8
  for (int t = 0; t < CHUNK; ++t) {
    unsigned int u = p[t * 256];
    float bre = __uint_as_float(u << 16);
    float bim = __uint_as_float(u & 0xffff0000u);
    float nre = fmaf(lre, sre, fmaf(-lim, sim, bre));
    float nim = fmaf(lre, sim, fmaf(lim, sre, bim));
    sre = nre; sim = nim;
  }
  E[(size_t)c * 256 + h] = make_float2(sre, sim);
}

// ---------------- scan pass 2: Kogge-Stone over chunks (block per channel) ---
__global__ void scan_pass2(const float2* __restrict__ E, const float* __restrict__ lam,
                           float2* __restrict__ Sc) {
  int h = blockIdx.x, c = threadIdx.x;  // c in [0, NCHUNKS)
  __shared__ float Ar[NCHUNKS], Ai[NCHUNKS], br[NCHUNKS], bi[NCHUNKS];
  float aR = lam[2 * DHID + 2 * h], aI = lam[2 * DHID + 2 * h + 1];
  float2 e = E[(size_t)c * 256 + h];
  float bR = e.x, bI = e.y;
  Ar[c] = aR; Ai[c] = aI; br[c] = bR; bi[c] = bI;
  __syncthreads();
  for (int off = 1; off < NCHUNKS; off <<= 1) {
    float paR = 0, paI = 0, pbR = 0, pbI = 0;
    bool has = (c >= off);
    if (has) { paR = Ar[c - off]; paI = Ai[c - off]; pbR = br[c - off]; pbI = bi[c - off]; }
    __syncthreads();
    if (has) {
      float nAR = aR * paR - aI * paI;
      float nAI = aR * paI + aI * paR;
      float nbR = aR * pbR - aI * pbI + bR;
      float nbI = aR * pbI + aI * pbR + bI;
      aR = nAR; aI = nAI; bR = nbR; bI = nbI;
      Ar[c] = aR; Ai[c] = aI; br[c] = bR; bi[c] = bI;
    }
    __syncthreads();
  }
  float inR = (c > 0) ? br[c - 1] : 0.f;
  float inI = (c > 0) ? bi[c - 1] : 0.f;
  Sc[(size_t)c * 256 + h] = make_float2(inR, inI);
}

// ---------------- scan pass 3: re-scan with carry, emit h bf16 interleaved ---
__global__ void scan_pass3(const unsigned int* __restrict__ Bu,
                           const float* __restrict__ lam,
                           const float2* __restrict__ Sc, bf16x2* __restrict__ Hb) {
  int c = blockIdx.x, h = threadIdx.x;
  float lre = lam[2 * h], lim = lam[2 * h + 1];
  float2 s0 = Sc[(size_t)c * 256 + h];
  float sre = s0.x, sim = s0.y;
  const unsigned int* p = Bu + (size_t)c * CHUNK * 256 + h;
  bf16x2* q = Hb + (size_t)c * CHUNK * 256 + h;
#pragma unroll 8
  for (int t = 0; t < CHUNK; ++t) {
    unsigned int u = p[t * 256];
    float bre = __uint_as_float(u << 16);
    float bim = __uint_as_float(u & 0xffff0000u);
    float nre = fmaf(lre, sre, fmaf(-lim, sim, bre));
    float nim = fmaf(lre, sim, fmaf(lim, sre, bim));
    sre = nre; sim = nim;
    bf16x2 o = {(bf16_t)sre, (bf16_t)sim};
    q[t * 256] = o;
  }
}

extern "C" void kernel_launch(void* const* d_in, const int* in_sizes, int n_in,
                              void* d_out, int out_size, void* d_ws, size_t ws_size,
                              hipStream_t stream) {
  const float* inputs    = (const float*)d_in[0];
  const float* nu_log    = (const float*)d_in[1];
  const float* theta_log = (const float*)d_in[2];
  const float* gamma_log = (const float*)d_in[3];
  const float* B_re      = (const float*)d_in[4];
  const float* B_im      = (const float*)d_in[5];
  const float* C_re      = (const float*)d_in[6];
  const float* C_im      = (const float*)d_in[7];
  const float* Dvec      = (const float*)d_in[8];
  float* out = (float*)d_out;

  char* w = (char*)d_ws;
  bf16_t* W1 = (bf16_t*)w;  w += (size_t)NCH * DMODEL * 2;    // 256 KB
  bf16_t* W2 = (bf16_t*)w;  w += (size_t)DMODEL * NCH * 2;    // 256 KB
  float* lam = (float*)w;   w += (size_t)4 * DHID * 4;        // 4 KB
  bf16_t* Bu = (bf16_t*)w;  w += (size_t)LSEQ * NCH * 2;      // 32 MB
  float2* E  = (float2*)w;  w += (size_t)NCHUNKS * DHID * 8;  // 1 MB
  float2* Sc = (float2*)w;  w += (size_t)NCHUNKS * DHID * 8;  // 1 MB
  bf16x2* Hb = (bf16x2*)w;  w += (size_t)LSEQ * NCH * 2;      // 32 MB

  prep_params<<<1, 256, 0, stream>>>(nu_log, theta_log, lam);
  pack_w1<<<NCH, DMODEL, 0, stream>>>(B_re, B_im, gamma_log, W1);
  pack_w2<<<DMODEL, NCH, 0, stream>>>(C_re, C_im, W2);

  gemm1<<<1024, 256, 0, stream>>>(inputs, W1, Bu);

  scan_pass1<<<NCHUNKS, 256, 0, stream>>>((const unsigned int*)Bu, lam, E);
  scan_pass2<<<DHID, NCHUNKS, 0, stream>>>(E, lam, Sc);
  scan_pass3<<<NCHUNKS, 256, 0, stream>>>((const unsigned int*)Bu, lam, Sc, Hb);

  gemm2<<<1024, 256, 0, stream>>>((const bf16_t*)Hb, W2, inputs, Dvec, out);
}